// Round 1
// baseline (34962.415 us; speedup 1.0000x reference)
//
#include <hip/hip_runtime.h>
#include <math.h>

// Problem constants
constexpr int C_B   = 512;
constexpr int C_T   = 365;
constexpr int C_IN  = 10;
constexpr int C_H   = 256;
constexpr int C_OUT = 20;

// Decomposition: 16 groups (32 batch rows each) x 16 blocks (16 hidden units each)
constexpr int N_GROUPS = 16;
constexpr int BT       = 32;   // batch tile per group
constexpr int JS       = 16;   // j-slice per block
constexpr int JBLK     = 16;   // blocks per group
constexpr int NTHREADS = 256;
constexpr int NBLOCKS  = N_GROUPS * JBLK; // 256

// Workspace layout (floats):
// h0[2][512][256] at 0 and 131072
// h1[2][512][256] at 262144 and 393216
// barrier counters (uint) at float offset 524288, 16 groups x 32-uint stride
constexpr int WS_H0   = 0;
constexpr int WS_H1   = 2 * C_B * C_H;
constexpr int WS_CTR  = 4 * C_B * C_H;   // float offset; counters live here

__device__ __forceinline__ void fma4(float4& a, const float4 w, const float4 h) {
    a.x += w.x * h.x; a.y += w.y * h.y; a.z += w.z * h.z; a.w += w.w * h.w;
}

__device__ __forceinline__ float hsum4(const float4 v) {
    return (v.x + v.y) + (v.z + v.w);
}

__device__ __forceinline__ float sigmoidf_(float v) {
    return 1.0f / (1.0f + expf(-v));
}

// Stage a contiguous [32][256] float tile from global into padded LDS [32][260]
__device__ __forceinline__ void stage_tile(const float* __restrict__ src,
                                           float (*lds)[C_H + 4], int tid) {
#pragma unroll
    for (int i = 0; i < 8; i++) {
        int e   = tid * 4 + i * 1024;
        int row = e >> 8;
        int col = e & 255;
        float4 v = *(const float4*)(src + e);
        *(float4*)(&lds[row][col]) = v;
    }
}

// One K=256 triple-gate GEMM pass: acc{r,z,n} for 2 batch rows.
__device__ __forceinline__ void pass256(const float* __restrict__ Wr,
                                        const float* __restrict__ Wz,
                                        const float* __restrict__ Wn,
                                        const float* hA, const float* hB,
                                        float& ar0, float& az0, float& an0,
                                        float& ar1, float& az1, float& an1) {
    float4 vr0 = {0,0,0,0}, vz0 = {0,0,0,0}, vn0 = {0,0,0,0};
    float4 vr1 = {0,0,0,0}, vz1 = {0,0,0,0}, vn1 = {0,0,0,0};
#pragma unroll 4
    for (int k = 0; k < C_H; k += 4) {
        float4 wr = *(const float4*)(Wr + k);
        float4 wz = *(const float4*)(Wz + k);
        float4 wn = *(const float4*)(Wn + k);
        float4 ha = *(const float4*)(hA + k);
        float4 hb = *(const float4*)(hB + k);
        fma4(vr0, wr, ha); fma4(vz0, wz, ha); fma4(vn0, wn, ha);
        fma4(vr1, wr, hb); fma4(vz1, wz, hb); fma4(vn1, wn, hb);
    }
    ar0 += hsum4(vr0); az0 += hsum4(vz0); an0 += hsum4(vn0);
    ar1 += hsum4(vr1); az1 += hsum4(vz1); an1 += hsum4(vn1);
}

// 16-block group barrier via monotonically increasing device-scope counter.
__device__ __forceinline__ void group_barrier(unsigned* c, unsigned target) {
    __syncthreads();
    if (threadIdx.x == 0) {
        __threadfence();  // release our h writes to device scope
        __hip_atomic_fetch_add(c, 1u, __ATOMIC_ACQ_REL, __HIP_MEMORY_SCOPE_AGENT);
        while (__hip_atomic_load(c, __ATOMIC_RELAXED, __HIP_MEMORY_SCOPE_AGENT) < target) {
            __builtin_amdgcn_s_sleep(4);
        }
        __threadfence();  // acquire others' h writes
    }
    __syncthreads();
}

__global__ void init_ctrs(float* ws) {
    unsigned* c = (unsigned*)(ws + WS_CTR);
    if (threadIdx.x < 512) c[threadIdx.x] = 0;
}

__global__ __launch_bounds__(NTHREADS, 1) void gru_persistent(
    const float* __restrict__ x,
    const float* __restrict__ Wih0, const float* __restrict__ Whh0,
    const float* __restrict__ bih0, const float* __restrict__ bhh0,
    const float* __restrict__ Wih1, const float* __restrict__ Whh1,
    const float* __restrict__ bih1, const float* __restrict__ bhh1,
    const float* __restrict__ Wout, const float* __restrict__ bout,
    float* __restrict__ out, float* __restrict__ ws) {

    __shared__ float lds_h[BT][C_H + 4];
    __shared__ float lds_x[BT][C_IN];
    __shared__ float lds_logits[BT * C_OUT];

    const int tid = threadIdx.x;
    const int g   = blockIdx.x >> 4;   // group 0..15
    const int r   = blockIdx.x & 15;   // j-block within group
    const int b0  = g * BT;
    const int j0  = r * JS;
    const int jl  = tid & 15;
    const int bp  = tid >> 4;          // 0..15
    const int bl  = bp * 2;            // this thread: batch rows bl, bl+1 (local)
    const int j   = j0 + jl;           // hidden unit 0..255

    float* h0buf[2] = { ws + WS_H0, ws + WS_H0 + C_B * C_H };
    float* h1buf[2] = { ws + WS_H1, ws + WS_H1 + C_B * C_H };
    unsigned* ctr = (unsigned*)(ws + WS_CTR) + g * 32;

    // Persistent per-thread data: W_ih0 rows (K=10) and biases for this j.
    float wir[C_IN], wiz[C_IN], win[C_IN];
#pragma unroll
    for (int i = 0; i < C_IN; i++) {
        wir[i] = Wih0[(j)         * C_IN + i];
        wiz[i] = Wih0[(C_H + j)   * C_IN + i];
        win[i] = Wih0[(2*C_H + j) * C_IN + i];
    }
    const float br0  = bih0[j]         + bhh0[j];
    const float bz0  = bih0[C_H + j]   + bhh0[C_H + j];
    const float bin0 = bih0[2*C_H + j];
    const float bhn0 = bhh0[2*C_H + j];
    const float br1  = bih1[j]         + bhh1[j];
    const float bz1  = bih1[C_H + j]   + bhh1[C_H + j];
    const float bin1 = bih1[2*C_H + j];
    const float bhn1 = bhh1[2*C_H + j];

    const float* Wr0 = Whh0 + (j)         * C_H;
    const float* Wz0 = Whh0 + (C_H + j)   * C_H;
    const float* Wn0 = Whh0 + (2*C_H + j) * C_H;
    const float* Air = Wih1 + (j)         * C_H;
    const float* Aiz = Wih1 + (C_H + j)   * C_H;
    const float* Ain = Wih1 + (2*C_H + j) * C_H;
    const float* Ahr = Whh1 + (j)         * C_H;
    const float* Ahz = Whh1 + (C_H + j)   * C_H;
    const float* Ahn = Whh1 + (2*C_H + j) * C_H;

    unsigned target = 0;
    int p = 0;

    for (int t = 0; t < C_T; t++) {
        // ---------------- Phase A: layer 0 ----------------
        // stage x tile [32][10]
        for (int u = tid; u < BT * C_IN; u += NTHREADS) {
            int bb = u / C_IN, i = u - bb * C_IN;
            lds_x[bb][i] = x[(b0 + bb) * (C_T * C_IN) + t * C_IN + i];
        }
        if (t > 0) stage_tile(h0buf[p] + b0 * C_H, lds_h, tid);
        __syncthreads();

        float ar_a = br0, az_a = bz0, ain_a = bin0, ahn_a = bhn0;
        float ar_b = br0, az_b = bz0, ain_b = bin0, ahn_b = bhn0;
#pragma unroll
        for (int i = 0; i < C_IN; i++) {
            float xa = lds_x[bl][i], xb = lds_x[bl + 1][i];
            ar_a  += xa * wir[i]; az_a += xa * wiz[i]; ain_a += xa * win[i];
            ar_b  += xb * wir[i]; az_b += xb * wiz[i]; ain_b += xb * win[i];
        }
        float hp_a = 0.0f, hp_b = 0.0f;
        if (t > 0) {
            hp_a = lds_h[bl][j];
            hp_b = lds_h[bl + 1][j];
            pass256(Wr0, Wz0, Wn0, &lds_h[bl][0], &lds_h[bl + 1][0],
                    ar_a, az_a, ahn_a, ar_b, az_b, ahn_b);
        }
        {
            float rr = sigmoidf_(ar_a), zz = sigmoidf_(az_a);
            float nn = tanhf(ain_a + rr * ahn_a);
            h0buf[1 - p][(b0 + bl) * C_H + j] = zz * (hp_a - nn) + nn;
            rr = sigmoidf_(ar_b); zz = sigmoidf_(az_b);
            nn = tanhf(ain_b + rr * ahn_b);
            h0buf[1 - p][(b0 + bl + 1) * C_H + j] = zz * (hp_b - nn) + nn;
        }
        target += JBLK;
        group_barrier(ctr, target);

        // ---------------- Phase B: layer 1 ----------------
        stage_tile(h0buf[1 - p] + b0 * C_H, lds_h, tid);
        __syncthreads();

        float ar1_a = br1, az1_a = bz1, ain1_a = bin1, ahn1_a = bhn1;
        float ar1_b = br1, az1_b = bz1, ain1_b = bin1, ahn1_b = bhn1;
        // pass 1: input gates from h0_new
        pass256(Air, Aiz, Ain, &lds_h[bl][0], &lds_h[bl + 1][0],
                ar1_a, az1_a, ain1_a, ar1_b, az1_b, ain1_b);
        __syncthreads();

        float h1p_a = 0.0f, h1p_b = 0.0f;
        if (t > 0) {
            stage_tile(h1buf[p] + b0 * C_H, lds_h, tid);
            __syncthreads();
            h1p_a = lds_h[bl][j];
            h1p_b = lds_h[bl + 1][j];
            pass256(Ahr, Ahz, Ahn, &lds_h[bl][0], &lds_h[bl + 1][0],
                    ar1_a, az1_a, ahn1_a, ar1_b, az1_b, ahn1_b);
        }
        {
            float rr = sigmoidf_(ar1_a), zz = sigmoidf_(az1_a);
            float nn = tanhf(ain1_a + rr * ahn1_a);
            h1buf[1 - p][(b0 + bl) * C_H + j] = zz * (h1p_a - nn) + nn;
            rr = sigmoidf_(ar1_b); zz = sigmoidf_(az1_b);
            nn = tanhf(ain1_b + rr * ahn1_b);
            h1buf[1 - p][(b0 + bl + 1) * C_H + j] = zz * (h1p_b - nn) + nn;
        }
        target += JBLK;
        group_barrier(ctr, target);
        p ^= 1;
    }

    // ---------------- Epilogue: classifier + softmax (block r==0 per group) ----
    if (r == 0) {
        stage_tile(h1buf[p] + b0 * C_H, lds_h, tid);
        __syncthreads();
        for (int u = tid; u < BT * C_OUT; u += NTHREADS) {
            int bb = u / C_OUT, o = u - bb * C_OUT;
            float acc = bout[o];
            const float* wrow = Wout + o * C_H;
            float4 v = {0,0,0,0};
#pragma unroll 4
            for (int k = 0; k < C_H; k += 4) {
                float4 w = *(const float4*)(wrow + k);
                float4 h = *(const float4*)(&lds_h[bb][k]);
                fma4(v, w, h);
            }
            lds_logits[bb * C_OUT + o] = acc + hsum4(v);
        }
        __syncthreads();
        if (tid < BT) {
            float mx = -1e30f;
#pragma unroll
            for (int o = 0; o < C_OUT; o++) mx = fmaxf(mx, lds_logits[tid * C_OUT + o]);
            float e[C_OUT];
            float s = 0.0f;
#pragma unroll
            for (int o = 0; o < C_OUT; o++) { e[o] = expf(lds_logits[tid * C_OUT + o] - mx); s += e[o]; }
            float inv = 1.0f / s;
#pragma unroll
            for (int o = 0; o < C_OUT; o++) out[(b0 + tid) * C_OUT + o] = e[o] * inv;
        }
    }
}

extern "C" void kernel_launch(void* const* d_in, const int* in_sizes, int n_in,
                              void* d_out, int out_size, void* d_ws, size_t ws_size,
                              hipStream_t stream) {
    const float* x    = (const float*)d_in[0];
    // d_in[1] = times (unused), d_in[2] = interpolation_method (unused)
    const float* Wih0 = (const float*)d_in[3];
    const float* Whh0 = (const float*)d_in[4];
    const float* bih0 = (const float*)d_in[5];
    const float* bhh0 = (const float*)d_in[6];
    const float* Wih1 = (const float*)d_in[7];
    const float* Whh1 = (const float*)d_in[8];
    const float* bih1 = (const float*)d_in[9];
    const float* bhh1 = (const float*)d_in[10];
    const float* Wout = (const float*)d_in[11];
    const float* bout = (const float*)d_in[12];
    float* out = (float*)d_out;
    float* ws  = (float*)d_ws;

    init_ctrs<<<1, 512, 0, stream>>>(ws);
    gru_persistent<<<NBLOCKS, NTHREADS, 0, stream>>>(
        x, Wih0, Whh0, bih0, bhh0, Wih1, Whh1, bih1, bhh1, Wout, bout, out, ws);
}